// Round 7
// baseline (5408.037 us; speedup 1.0000x reference)
//
#include <hip/hip_runtime.h>

// Seq2Seq LSTM (B=2048, T=100, E=512, FUTURE=10, POSE=34). FP32 in/out.
// bf16 MFMA, SPLIT WEIGHTS (W = W_hi + W_lo bf16, K=1024/phase), h bf16,
// c fp32. R6 tiling: 256 blocks = 16 e-slices (32 e-cols) x 16 R-groups
// (128 batch rows) -> each W chunk amortized over 128 rows, halving L2/LLC
// W traffic vs R5 (16 sharers/slice instead of 32).
//  - 512 thr = 8 waves: (es2 e-half, rb batch-half, kg K-parity).
//  - A panel (128 rows x K512, 128 KB) staged to LDS per phase, XOR-swizzled;
//    K-loops barrier-free; cell2 re-stages A between its two GEMM phases.
//  - W streamed global->VGPR from pre-swizzled layout (1KB coalesced units),
//    register ping-pong prefetch 1 chunk ahead.
//  - kg partials reduced via LDS once; per-lane i,f,g,o LSTM epilogue.
//  - blockIdx low 4 bits = e16 so (under %8 XCD heuristic) each XCD serves
//    2 half-slices (~1.6 MB weights) L2-resident across all timesteps.

#define TSEQ 100
#define FUT 10
#define POSE_D 34
#define EDIM 512
#define BDIM 2048

typedef __bf16 bf16x8 __attribute__((ext_vector_type(8)));
typedef float floatx4 __attribute__((ext_vector_type(4)));
typedef short shortx8 __attribute__((ext_vector_type(8)));

__device__ __forceinline__ float bf2f(short s) {
    unsigned int u = ((unsigned int)(unsigned short)s) << 16;
    float f;
    __builtin_memcpy(&f, &u, 4);
    return f;
}
__device__ __forceinline__ short f2bf(float f) {
    unsigned int u;
    __builtin_memcpy(&u, &f, 4);
    u += 0x7fffu + ((u >> 16) & 1u);
    return (short)(u >> 16);
}
__device__ __forceinline__ float fsig(float x) { return 1.f / (1.f + __expf(-x)); }
__device__ __forceinline__ float ftanh(float x) {
    float ax = fabsf(x);
    float t = __expf(-2.f * ax);
    float r = (1.f - t) / (1.f + t);
    return x < 0.f ? -r : r;
}

// Swizzled W stream (1KB wave units):
//   unit(e0,kcp,es,g,kk) = (((e0*16+kcp)*4+es)*4+g)*2+kk ; shorts = unit*512+lane*8
//   src row = g*512 + e0*64 + es*16 + (lane&15), k = (kcp&7)*64 + kk*32 + (lane>>4)*8
//   kcp<8 -> hi plane, kcp>=8 -> lo plane. M1 same with NW=1 (kcp=0).

template <bool HAS_X, bool TWO_H>
__global__ __launch_bounds__(512, 2) void lstm_cell_kernel(
    const float* __restrict__ xptr, const short* __restrict__ M1,
    const short* __restrict__ A1, const short* __restrict__ W1,
    const short* __restrict__ A2, const short* __restrict__ W2,
    const float* __restrict__ bias, float* __restrict__ c_io,
    short* __restrict__ h_out, float* __restrict__ hf_out) {
    __shared__ __align__(16) short lds[HAS_X ? 73728 : 65536];
    const int tid = threadIdx.x;
    const int lane = tid & 63;
    const int wv = tid >> 6;
    const int es2 = wv & 1;        // 16-col e half within the 32-col slice
    const int rb = (wv >> 1) & 1;  // batch half (64 rows)
    const int kg = wv >> 2;        // K parity
    const int m = lane & 15;
    const int q = lane >> 4;
    const int e16 = blockIdx.x & 15;
    const int R0 = (blockIdx.x >> 4) * 128;
    const int e0 = e16 >> 1;               // W-stream region
    const int es = (e16 & 1) * 2 + es2;    // sub-slice within region
    constexpr int AOFF = HAS_X ? 8192 : 0; // shorts; x panel occupies [0,8192)

    floatx4 acc[4][4];
#pragma unroll
    for (int ri = 0; ri < 4; ++ri)
#pragma unroll
        for (int g = 0; g < 4; ++g) acc[ri][g] = {0.f, 0.f, 0.f, 0.f};

    bf16x8 rW0[8], rW1[8];

    auto loadW = [&](const short* __restrict__ W, int kcp, bf16x8(&w_)[8]) {
        const short* P = W + (long)((e0 * 16 + kcp) * 4 + es) * 4096 + lane * 8;
#pragma unroll
        for (int i = 0; i < 8; ++i) w_[i] = *(const bf16x8*)(P + i * 512);
    };
    auto loadM1 = [&](bf16x8(&w_)[8]) {
        const short* P = M1 + (long)((e0 * 4 + es) * 8) * 512 + lane * 8;
#pragma unroll
        for (int i = 0; i < 8; ++i) w_[i] = *(const bf16x8*)(P + i * 512);
    };

    // h-chunk: A rows rb*64+ri*16+m from the 128-row panel, XOR-swizzled.
    auto do_chunk = [&](int kcp, bf16x8(&w_)[8]) {
        const int k8 = (kcp & 7) * 8;
#pragma unroll
        for (int kk = 0; kk < 2; ++kk) {
            bf16x8 a[4];
#pragma unroll
            for (int ri = 0; ri < 4; ++ri) {
                const int row = rb * 64 + ri * 16 + m;
                a[ri] = *(const bf16x8*)(lds + AOFF + row * 512 +
                                         ((k8 | (((kk * 4 + q) ^ row) & 7)) << 3));
            }
#pragma unroll
            for (int ri = 0; ri < 4; ++ri)
#pragma unroll
                for (int g = 0; g < 4; ++g)
                    acc[ri][g] = __builtin_amdgcn_mfma_f32_16x16x32_bf16(
                        a[ri], w_[g * 2 + kk], acc[ri][g], 0, 0, 0);
        }
    };
    auto do_x = [&](bf16x8(&w_)[8]) {  // x panel: 128 rows x 64 K at lds[0]
#pragma unroll
        for (int kk = 0; kk < 2; ++kk) {
            bf16x8 a[4];
#pragma unroll
            for (int ri = 0; ri < 4; ++ri) {
                const int row = rb * 64 + ri * 16 + m;
                a[ri] = *(const bf16x8*)(lds + row * 64 + (((kk * 4 + q) ^ (row & 7)) << 3));
            }
#pragma unroll
            for (int ri = 0; ri < 4; ++ri)
#pragma unroll
                for (int g = 0; g < 4; ++g)
                    acc[ri][g] = __builtin_amdgcn_mfma_f32_16x16x32_bf16(
                        a[ri], w_[g * 2 + kk], acc[ri][g], 0, 0, 0);
        }
    };

    // Stage a 128-row x 512-K bf16 panel into LDS (XOR-swizzled 16B units).
    auto stageA = [&](const short* __restrict__ G, int dst) {
#pragma unroll
        for (int i = 0; i < 16; ++i) {
            const int u = tid + (i << 9);
            const int r = u >> 6, c = u & 63;
            const shortx8 v = *(const shortx8*)(G + (long)r * 512 + (c << 3));
            *(shortx8*)(lds + dst + r * 512 + (((c & 56) | ((c ^ r) & 7)) << 3)) = v;
        }
    };

    // 16-chunk barrier-free K-loop with W register ping-pong (chunks c≡kg mod 2).
    auto loop16 = [&](const short* __restrict__ W) {
        int c = kg;
#pragma unroll 1
        for (;;) {
            const int nxt = c + 2;
            if (nxt < 16) loadW(W, nxt, rW1);
            do_chunk(c, rW0);
            c = nxt;
            if (c >= 16) break;
            const int nx2 = c + 2;
            if (nx2 < 16) loadW(W, nx2, rW0);
            do_chunk(c, rW1);
            c = nx2;
            if (c >= 16) break;
        }
    };

    if constexpr (HAS_X) {
        // x panel zero (K pad 34->64) + scalar fill + A1 panel; NT=17 chunks.
        floatx4 z = {0.f, 0.f, 0.f, 0.f};
        *(floatx4*)(lds + tid * 16) = z;
        *(floatx4*)(lds + tid * 16 + 8) = z;
        stageA(A1 + (long)R0 * 512, AOFF);
        __syncthreads();  // zero visible before scalar overwrite
        for (int idx = tid; idx < 128 * POSE_D; idx += 512) {
            const int r = idx / POSE_D;
            const int c = idx - r * POSE_D;
            lds[r * 64 + (((c >> 3) ^ (r & 7)) << 3) + (c & 7)] =
                f2bf(xptr[(long)(R0 + r) * (TSEQ * POSE_D) + c]);
        }
        if (kg == 0) loadM1(rW0);
        else loadW(W1, 0, rW0);
        __syncthreads();
        int c = kg;
#pragma unroll 1
        for (;;) {
            const int nxt = c + 2;
            if (nxt < 17) loadW(W1, nxt - 1, rW1);
            if (c == 0) do_x(rW0);
            else do_chunk(c - 1, rW0);
            c = nxt;
            if (c >= 17) break;
            const int nx2 = c + 2;
            if (nx2 < 17) loadW(W1, nx2 - 1, rW0);
            do_chunk(c - 1, rW1);
            c = nx2;
            if (c >= 17) break;
        }
    } else {
        stageA(A1 + (long)R0 * 512, AOFF);
        loadW(W1, kg, rW0);
        __syncthreads();
        loop16(W1);
        if constexpr (TWO_H) {
            __syncthreads();  // all A1 reads done before overwrite
            stageA(A2 + (long)R0 * 512, AOFF);
            loadW(W2, kg, rW0);
            __syncthreads();
            loop16(W2);
        }
    }

    // ---- cross-kg reduction via LDS (overlay; post-barrier) ----
    __syncthreads();
    float* ldsf = (float*)lds;
    const int L = (rb * 2 + es2) * 64 + lane;
    if (kg == 1) {
#pragma unroll
        for (int ri = 0; ri < 4; ++ri)
#pragma unroll
            for (int g = 0; g < 4; ++g) {
                const int f4 = ri * 4 + g;
                *(floatx4*)(ldsf + L * 68 + ((f4 ^ m) << 2)) = acc[ri][g];
            }
    }
    __syncthreads();
    if (kg == 0) {
#pragma unroll
        for (int ri = 0; ri < 4; ++ri)
#pragma unroll
            for (int g = 0; g < 4; ++g) {
                const int f4 = ri * 4 + g;
                acc[ri][g] += *(const floatx4*)(ldsf + L * 68 + ((f4 ^ m) << 2));
            }
        // ---- fused LSTM pointwise epilogue (per-lane i,f,g,o) ----
        const int e = e16 * 32 + es2 * 16 + m;
        const float bi = bias[e];
        const float bfv = bias[512 + e];
        const float bg = bias[1024 + e];
        const float bo = bias[1536 + e];
#pragma unroll
        for (int ri = 0; ri < 4; ++ri) {
#pragma unroll
            for (int rg = 0; rg < 4; ++rg) {
                const int br = R0 + rb * 64 + ri * 16 + q * 4 + rg;  // C/D: row=q*4+reg
                const long cidx = (long)br * EDIM + e;
                const float iv = fsig(acc[ri][0][rg] + bi);
                const float fv = fsig(acc[ri][1][rg] + bfv);
                const float gv = ftanh(acc[ri][2][rg] + bg);
                const float ov = fsig(acc[ri][3][rg] + bo);
                const float cn = fv * c_io[cidx] + iv * gv;
                c_io[cidx] = cn;
                const float hv = ov * ftanh(cn);
                h_out[cidx] = f2bf(hv);
                if (hf_out) hf_out[cidx] = hv;
            }
        }
    }
}

__global__ __launch_bounds__(256) void zero_kernel(unsigned int* __restrict__ p, int n) {
    int i = blockIdx.x * 256 + threadIdx.x;
    const int stride = gridDim.x * 256;
    for (; i < n; i += stride) p[i] = 0u;
}

// bias1 = bih1 + bhh1 + Wih1 @ enc_lin_b ; bias2 = bih2+bhh2 ; biasd = dbih+dbhh
__global__ __launch_bounds__(256) void prep_bias(
    const float* __restrict__ bih1, const float* __restrict__ bhh1,
    const float* __restrict__ Wih1, const float* __restrict__ encb,
    const float* __restrict__ bih2, const float* __restrict__ bhh2,
    const float* __restrict__ dbih, const float* __restrict__ dbhh,
    float* __restrict__ bias1, float* __restrict__ bias2, float* __restrict__ biasd) {
    const int n = blockIdx.x * 256 + threadIdx.x;
    if (n >= 2048) return;
    float s = bih1[n] + bhh1[n];
    const float* wr = Wih1 + (long)n * EDIM;
    for (int j = 0; j < EDIM; ++j) s += wr[j] * encb[j];
    bias1[n] = s;
    bias2[n] = bih2[n] + bhh2[n];
    biasd[n] = dbih[n] + dbhh[n];
}

// Swizzle fp32 W[2048x512] (+optional addend) into hi|lo bf16 frag-stream.
__global__ __launch_bounds__(256) void swizzle_w(const float* __restrict__ a,
                                                 const float* __restrict__ b,
                                                 short* __restrict__ o) {
    const int idx = blockIdx.x * 256 + threadIdx.x;
    if (idx >= 262144) return;
    const int lane = idx & 63, kk = (idx >> 6) & 1, g = (idx >> 7) & 3;
    const int w = (idx >> 9) & 3, kc = (idx >> 11) & 15, e0 = idx >> 15;
    const int row = g * 512 + e0 * 64 + w * 16 + (lane & 15);
    const int ks = (kc & 7) * 64 + kk * 32 + (lane >> 4) * 8;
    const bool lo = kc >= 8;
    shortx8 outv;
#pragma unroll
    for (int j = 0; j < 8; ++j) {
        const long si = (long)row * EDIM + ks + j;
        const float v = b ? (a[si] + b[si]) : a[si];
        const short hi = f2bf(v);
        outv[j] = lo ? f2bf(v - bf2f(hi)) : hi;
    }
    *(shortx8*)(o + (long)idx * 8) = outv;
}

// M1 = Wih1 @ enc_lin_W (K pad 34->64), swizzled, one thread per element.
__global__ __launch_bounds__(256) void swizzle_M1(const float* __restrict__ Wih1,
                                                  const float* __restrict__ encW,
                                                  short* __restrict__ o) {
    const int idx = blockIdx.x * 256 + threadIdx.x;
    if (idx >= 131072) return;
    const int u = idx >> 3, j = idx & 7;
    const int lane = u & 63, kk = (u >> 6) & 1, g = (u >> 7) & 3;
    const int w = (u >> 9) & 3, e0 = u >> 11;
    const int row = g * 512 + e0 * 64 + w * 16 + (lane & 15);
    const int k = kk * 32 + (lane >> 4) * 8 + j;
    float s = 0.f;
    if (k < POSE_D) {
        const float* wr = Wih1 + (long)row * EDIM;
        for (int jj = 0; jj < EDIM; ++jj) s += wr[jj] * encW[jj * POSE_D + k];
    }
    o[(long)u * 8 + j] = f2bf(s);
}

// out[b,f,p] = hf[b,:] . dec_lin_W[p,:] + dec_lin_b[p]  (pure fp32)
__global__ __launch_bounds__(64) void out_proj(const float* __restrict__ hf,
                                               const float* __restrict__ W,
                                               const float* __restrict__ bias,
                                               float* __restrict__ out, int f) {
    const int b = blockIdx.x;
    __shared__ float hrow[EDIM];
    const int lane = threadIdx.x;
    *(floatx4*)(hrow + lane * 8) = *(const floatx4*)(hf + (long)b * EDIM + lane * 8);
    *(floatx4*)(hrow + lane * 8 + 4) = *(const floatx4*)(hf + (long)b * EDIM + lane * 8 + 4);
    __syncthreads();
    if (lane < POSE_D) {
        float acc = bias[lane];
        const float* wr = W + (long)lane * EDIM;
        for (int e = 0; e < EDIM; e += 4) {
            const floatx4 wv = *(const floatx4*)(wr + e);
            acc += hrow[e] * wv[0] + hrow[e + 1] * wv[1] + hrow[e + 2] * wv[2] + hrow[e + 3] * wv[3];
        }
        out[((long)b * FUT + f) * POSE_D + lane] = acc;
    }
}

extern "C" void kernel_launch(void* const* d_in, const int* in_sizes, int n_in,
                              void* d_out, int out_size, void* d_ws, size_t ws_size,
                              hipStream_t stream) {
    const float* x = (const float*)d_in[0];
    const float* encW = (const float*)d_in[1];
    const float* encb = (const float*)d_in[2];
    const float* Wih1 = (const float*)d_in[3];
    const float* Whh1 = (const float*)d_in[4];
    const float* bih1 = (const float*)d_in[5];
    const float* bhh1 = (const float*)d_in[6];
    const float* Wih2 = (const float*)d_in[7];
    const float* Whh2 = (const float*)d_in[8];
    const float* bih2 = (const float*)d_in[9];
    const float* bhh2 = (const float*)d_in[10];
    const float* dWih = (const float*)d_in[11];
    const float* dWhh = (const float*)d_in[12];
    const float* dbih = (const float*)d_in[13];
    const float* dbhh = (const float*)d_in[14];
    const float* oW = (const float*)d_in[15];
    const float* ob = (const float*)d_in[16];
    float* out = (float*)d_out;

    char* ws = (char*)d_ws;
    size_t off = 0;
    auto alloc = [&](size_t bytes) -> char* {
        char* p = ws + off;
        off = (off + bytes + 255) & ~(size_t)255;
        return p;
    };
    const size_t HB = (size_t)BDIM * EDIM * 2;   // 2 MB bf16 state
    const size_t CB = (size_t)BDIM * EDIM * 4;   // 4 MB fp32 state
    const size_t WSZ = (size_t)262144 * 16;      // 4 MB swizzled split-W
    // zero-region (contiguous): h1_0, h2_0, c1, c2
    short* h1_0 = (short*)alloc(HB);
    short* h2_0 = (short*)alloc(HB);
    float* c1 = (float*)alloc(CB);
    float* c2 = (float*)alloc(CB);
    short* h1_1 = (short*)alloc(HB);
    short* h2_1 = (short*)alloc(HB);
    float* hf0 = (float*)alloc(CB);
    float* hf1 = (float*)alloc(CB);
    short* M1 = (short*)alloc((size_t)16384 * 16);
    short* sWhh1 = (short*)alloc(WSZ);
    short* sWih2 = (short*)alloc(WSZ);
    short* sWhh2 = (short*)alloc(WSZ);
    short* sdWhh = (short*)alloc(WSZ);
    short* sWsum = (short*)alloc(WSZ);
    float* bias1 = (float*)alloc(2048 * 4);
    float* bias2 = (float*)alloc(2048 * 4);
    float* biasd = (float*)alloc(2048 * 4);
    (void)ws_size; (void)in_sizes; (void)n_in; (void)out_size;

    zero_kernel<<<2048, 256, 0, stream>>>((unsigned int*)h1_0, (int)((2 * HB + 2 * CB) / 4));
    prep_bias<<<8, 256, 0, stream>>>(bih1, bhh1, Wih1, encb, bih2, bhh2, dbih, dbhh,
                                     bias1, bias2, biasd);
    swizzle_M1<<<512, 256, 0, stream>>>(Wih1, encW, M1);
    swizzle_w<<<1024, 256, 0, stream>>>(Whh1, nullptr, sWhh1);
    swizzle_w<<<1024, 256, 0, stream>>>(Wih2, nullptr, sWih2);
    swizzle_w<<<1024, 256, 0, stream>>>(Whh2, nullptr, sWhh2);
    swizzle_w<<<1024, 256, 0, stream>>>(dWhh, nullptr, sdWhh);
    swizzle_w<<<1024, 256, 0, stream>>>(dWih, dWhh, sWsum);

    dim3 grid(256), blk(512);
    short *h1p = h1_0, *h1n = h1_1, *h2p = h2_0, *h2n = h2_1;
    for (int t = 0; t < TSEQ; ++t) {
        lstm_cell_kernel<true, false><<<grid, blk, 0, stream>>>(
            x + t * POSE_D, M1, h1p, sWhh1, nullptr, nullptr,
            bias1, c1, h1n, nullptr);
        lstm_cell_kernel<false, true><<<grid, blk, 0, stream>>>(
            nullptr, nullptr, h1n, sWih2, h2p, sWhh2,
            bias2, c2, h2n, nullptr);
        short* t1 = h1p; h1p = h1n; h1n = t1;
        short* t2 = h2p; h2p = h2n; h2n = t2;
    }
    // decoder: bf16 h ping-pong reuses freed h1 buffers; fp32 copy for out_proj
    short* hd0 = h1_1;
    short* hd1 = h1_0;
    lstm_cell_kernel<false, false><<<grid, blk, 0, stream>>>(
        nullptr, nullptr, h2p, sdWhh, nullptr, nullptr,
        biasd, c2, hd0, hf0);
    out_proj<<<BDIM, 64, 0, stream>>>(hf0, oW, ob, out, 0);
    short *dp = hd0, *dn = hd1;
    float *fp = hf0, *fn = hf1;
    for (int f = 1; f < FUT; ++f) {
        lstm_cell_kernel<false, false><<<grid, blk, 0, stream>>>(
            nullptr, nullptr, dp, sWsum, nullptr, nullptr,
            biasd, c2, dn, fn);
        out_proj<<<BDIM, 64, 0, stream>>>(fn, oW, ob, out, f);
        short* tt = dp; dp = dn; dn = tt;
        float* tf = fp; fp = fn; fn = tf;
    }
}

// Round 8
// 4652.202 us; speedup vs baseline: 1.1625x; 1.1625x over previous
//
#include <hip/hip_runtime.h>

// Seq2Seq LSTM (B=2048, T=100, E=512, FUTURE=10, POSE=34). FP32 in/out.
// bf16 MFMA, h-state bf16, c-state fp32.
// R8 numerics: ENCODER weights single bf16 plane (hi only; error analysis in
// journal — h-rounding dominates), DECODER keeps split hi+lo (W=W_hi+W_lo)
// since it feeds the fp32 output projection directly. M1 single-plane as ever.
// Tiling (from R6): 256 blocks = 16 e-slices (32 e-cols) x 16 R-groups
// (128 batch rows); 512 thr = 8 waves (es2, rb, kg K-parity).
//  - A panel (128 rows x K512) staged to LDS once per phase, XOR-swizzled;
//    K-loops barrier-free; cell2 re-stages A between its two phases.
//  - W streamed global->VGPR from pre-swizzled layout (1KB coalesced units),
//    register ping-pong prefetch 1 chunk ahead.
//  - kg partials reduced via LDS once; per-lane i,f,g,o LSTM epilogue.

#define TSEQ 100
#define FUT 10
#define POSE_D 34
#define EDIM 512
#define BDIM 2048

typedef __bf16 bf16x8 __attribute__((ext_vector_type(8)));
typedef float floatx4 __attribute__((ext_vector_type(4)));
typedef short shortx8 __attribute__((ext_vector_type(8)));

__device__ __forceinline__ float bf2f(short s) {
    unsigned int u = ((unsigned int)(unsigned short)s) << 16;
    float f;
    __builtin_memcpy(&f, &u, 4);
    return f;
}
__device__ __forceinline__ short f2bf(float f) {
    unsigned int u;
    __builtin_memcpy(&u, &f, 4);
    u += 0x7fffu + ((u >> 16) & 1u);
    return (short)(u >> 16);
}
__device__ __forceinline__ float fsig(float x) { return 1.f / (1.f + __expf(-x)); }
__device__ __forceinline__ float ftanh(float x) {
    float ax = fabsf(x);
    float t = __expf(-2.f * ax);
    float r = (1.f - t) / (1.f + t);
    return x < 0.f ? -r : r;
}

// Swizzled W stream (1KB wave units):
//   unit(e0,kcp,es,g,kk) = (((e0*16+kcp)*4+es)*4+g)*2+kk ; shorts = unit*512+lane*8
//   src row = g*512 + e0*64 + es*16 + (lane&15), k = (kcp&7)*64 + kk*32 + (lane>>4)*8
//   kcp<8 -> hi plane, kcp>=8 -> lo plane. M1 same with NW=1 (kcp=0).

// NP = weight planes used (1 = hi only, 2 = hi+lo split).
template <bool HAS_X, bool TWO_H, int NP>
__global__ __launch_bounds__(512, 2) void lstm_cell_kernel(
    const float* __restrict__ xptr, const short* __restrict__ M1,
    const short* __restrict__ A1, const short* __restrict__ W1,
    const short* __restrict__ A2, const short* __restrict__ W2,
    const float* __restrict__ bias, float* __restrict__ c_io,
    short* __restrict__ h_out, float* __restrict__ hf_out) {
    __shared__ __align__(16) short lds[HAS_X ? 73728 : 65536];
    const int tid = threadIdx.x;
    const int lane = tid & 63;
    const int wv = tid >> 6;
    const int es2 = wv & 1;        // 16-col e half within the 32-col slice
    const int rb = (wv >> 1) & 1;  // batch half (64 rows)
    const int kg = wv >> 2;        // K parity
    const int m = lane & 15;
    const int q = lane >> 4;
    const int e16 = blockIdx.x & 15;
    const int R0 = (blockIdx.x >> 4) * 128;
    const int e0 = e16 >> 1;               // W-stream region
    const int es = (e16 & 1) * 2 + es2;    // sub-slice within region
    constexpr int PH = NP * 8;             // chunks per GEMM phase
    constexpr int AOFF = HAS_X ? 8192 : 0; // shorts; x panel occupies [0,8192)

    floatx4 acc[4][4];
#pragma unroll
    for (int ri = 0; ri < 4; ++ri)
#pragma unroll
        for (int g = 0; g < 4; ++g) acc[ri][g] = {0.f, 0.f, 0.f, 0.f};

    bf16x8 rW0[8], rW1[8];

    auto loadW = [&](const short* __restrict__ W, int kcp, bf16x8(&w_)[8]) {
        const short* P = W + (long)((e0 * 16 + kcp) * 4 + es) * 4096 + lane * 8;
#pragma unroll
        for (int i = 0; i < 8; ++i) w_[i] = *(const bf16x8*)(P + i * 512);
    };
    auto loadM1 = [&](bf16x8(&w_)[8]) {
        const short* P = M1 + (long)((e0 * 4 + es) * 8) * 512 + lane * 8;
#pragma unroll
        for (int i = 0; i < 8; ++i) w_[i] = *(const bf16x8*)(P + i * 512);
    };

    // h-chunk: A rows rb*64+ri*16+m from the 128-row panel, XOR-swizzled.
    auto do_chunk = [&](int kcp, bf16x8(&w_)[8]) {
        const int k8 = (kcp & 7) * 8;
#pragma unroll
        for (int kk = 0; kk < 2; ++kk) {
            bf16x8 a[4];
#pragma unroll
            for (int ri = 0; ri < 4; ++ri) {
                const int row = rb * 64 + ri * 16 + m;
                a[ri] = *(const bf16x8*)(lds + AOFF + row * 512 +
                                         ((k8 | (((kk * 4 + q) ^ row) & 7)) << 3));
            }
#pragma unroll
            for (int ri = 0; ri < 4; ++ri)
#pragma unroll
                for (int g = 0; g < 4; ++g)
                    acc[ri][g] = __builtin_amdgcn_mfma_f32_16x16x32_bf16(
                        a[ri], w_[g * 2 + kk], acc[ri][g], 0, 0, 0);
        }
    };
    auto do_x = [&](bf16x8(&w_)[8]) {  // x panel: 128 rows x 64 K at lds[0]
#pragma unroll
        for (int kk = 0; kk < 2; ++kk) {
            bf16x8 a[4];
#pragma unroll
            for (int ri = 0; ri < 4; ++ri) {
                const int row = rb * 64 + ri * 16 + m;
                a[ri] = *(const bf16x8*)(lds + row * 64 + (((kk * 4 + q) ^ (row & 7)) << 3));
            }
#pragma unroll
            for (int ri = 0; ri < 4; ++ri)
#pragma unroll
                for (int g = 0; g < 4; ++g)
                    acc[ri][g] = __builtin_amdgcn_mfma_f32_16x16x32_bf16(
                        a[ri], w_[g * 2 + kk], acc[ri][g], 0, 0, 0);
        }
    };

    // Stage a 128-row x 512-K bf16 panel into LDS (XOR-swizzled 16B units).
    auto stageA = [&](const short* __restrict__ G, int dst) {
#pragma unroll
        for (int i = 0; i < 16; ++i) {
            const int u = tid + (i << 9);
            const int r = u >> 6, c = u & 63;
            const shortx8 v = *(const shortx8*)(G + (long)r * 512 + (c << 3));
            *(shortx8*)(lds + dst + r * 512 + (((c & 56) | ((c ^ r) & 7)) << 3)) = v;
        }
    };

    // PH-chunk barrier-free K-loop with W register ping-pong (chunks c≡kg mod 2).
    auto loopP = [&](const short* __restrict__ W) {
        int c = kg;
#pragma unroll 1
        for (;;) {
            const int nxt = c + 2;
            if (nxt < PH) loadW(W, nxt, rW1);
            do_chunk(c, rW0);
            c = nxt;
            if (c >= PH) break;
            const int nx2 = c + 2;
            if (nx2 < PH) loadW(W, nx2, rW0);
            do_chunk(c, rW1);
            c = nx2;
            if (c >= PH) break;
        }
    };

    if constexpr (HAS_X) {
        // x panel zero (K pad 34->64) + scalar fill + A1 panel; NT=1+PH chunks.
        constexpr int NT = 1 + PH;
        floatx4 z = {0.f, 0.f, 0.f, 0.f};
        *(floatx4*)(lds + tid * 16) = z;
        *(floatx4*)(lds + tid * 16 + 8) = z;
        stageA(A1 + (long)R0 * 512, AOFF);
        __syncthreads();  // zero visible before scalar overwrite
        for (int idx = tid; idx < 128 * POSE_D; idx += 512) {
            const int r = idx / POSE_D;
            const int c = idx - r * POSE_D;
            lds[r * 64 + (((c >> 3) ^ (r & 7)) << 3) + (c & 7)] =
                f2bf(xptr[(long)(R0 + r) * (TSEQ * POSE_D) + c]);
        }
        if (kg == 0) loadM1(rW0);
        else loadW(W1, 0, rW0);
        __syncthreads();
        int c = kg;
#pragma unroll 1
        for (;;) {
            const int nxt = c + 2;
            if (nxt < NT) loadW(W1, nxt - 1, rW1);
            if (c == 0) do_x(rW0);
            else do_chunk(c - 1, rW0);
            c = nxt;
            if (c >= NT) break;
            const int nx2 = c + 2;
            if (nx2 < NT) loadW(W1, nx2 - 1, rW0);
            do_chunk(c - 1, rW1);
            c = nx2;
            if (c >= NT) break;
        }
    } else {
        stageA(A1 + (long)R0 * 512, AOFF);
        loadW(W1, kg, rW0);
        __syncthreads();
        loopP(W1);
        if constexpr (TWO_H) {
            __syncthreads();  // all A1 reads done before overwrite
            stageA(A2 + (long)R0 * 512, AOFF);
            loadW(W2, kg, rW0);
            __syncthreads();
            loopP(W2);
        }
    }

    // ---- cross-kg reduction via LDS (overlay; post-barrier) ----
    __syncthreads();
    float* ldsf = (float*)lds;
    const int L = (rb * 2 + es2) * 64 + lane;
    if (kg == 1) {
#pragma unroll
        for (int ri = 0; ri < 4; ++ri)
#pragma unroll
            for (int g = 0; g < 4; ++g) {
                const int f4 = ri * 4 + g;
                *(floatx4*)(ldsf + L * 68 + ((f4 ^ m) << 2)) = acc[ri][g];
            }
    }
    __syncthreads();
    if (kg == 0) {
#pragma unroll
        for (int ri = 0; ri < 4; ++ri)
#pragma unroll
            for (int g = 0; g < 4; ++g) {
                const int f4 = ri * 4 + g;
                acc[ri][g] += *(const floatx4*)(ldsf + L * 68 + ((f4 ^ m) << 2));
            }
        // ---- fused LSTM pointwise epilogue (per-lane i,f,g,o) ----
        const int e = e16 * 32 + es2 * 16 + m;
        const float bi = bias[e];
        const float bfv = bias[512 + e];
        const float bg = bias[1024 + e];
        const float bo = bias[1536 + e];
#pragma unroll
        for (int ri = 0; ri < 4; ++ri) {
#pragma unroll
            for (int rg = 0; rg < 4; ++rg) {
                const int br = R0 + rb * 64 + ri * 16 + q * 4 + rg;  // C/D: row=q*4+reg
                const long cidx = (long)br * EDIM + e;
                const float iv = fsig(acc[ri][0][rg] + bi);
                const float fv = fsig(acc[ri][1][rg] + bfv);
                const float gv = ftanh(acc[ri][2][rg] + bg);
                const float ov = fsig(acc[ri][3][rg] + bo);
                const float cn = fv * c_io[cidx] + iv * gv;
                c_io[cidx] = cn;
                const float hv = ov * ftanh(cn);
                h_out[cidx] = f2bf(hv);
                if (hf_out) hf_out[cidx] = hv;
            }
        }
    }
}

__global__ __launch_bounds__(256) void zero_kernel(unsigned int* __restrict__ p, int n) {
    int i = blockIdx.x * 256 + threadIdx.x;
    const int stride = gridDim.x * 256;
    for (; i < n; i += stride) p[i] = 0u;
}

// bias1 = bih1 + bhh1 + Wih1 @ enc_lin_b ; bias2 = bih2+bhh2 ; biasd = dbih+dbhh
__global__ __launch_bounds__(256) void prep_bias(
    const float* __restrict__ bih1, const float* __restrict__ bhh1,
    const float* __restrict__ Wih1, const float* __restrict__ encb,
    const float* __restrict__ bih2, const float* __restrict__ bhh2,
    const float* __restrict__ dbih, const float* __restrict__ dbhh,
    float* __restrict__ bias1, float* __restrict__ bias2, float* __restrict__ biasd) {
    const int n = blockIdx.x * 256 + threadIdx.x;
    if (n >= 2048) return;
    float s = bih1[n] + bhh1[n];
    const float* wr = Wih1 + (long)n * EDIM;
    for (int j = 0; j < EDIM; ++j) s += wr[j] * encb[j];
    bias1[n] = s;
    bias2[n] = bih2[n] + bhh2[n];
    biasd[n] = dbih[n] + dbhh[n];
}

// Swizzle fp32 W[2048x512] (+optional addend) into hi|lo bf16 frag-stream.
__global__ __launch_bounds__(256) void swizzle_w(const float* __restrict__ a,
                                                 const float* __restrict__ b,
                                                 short* __restrict__ o) {
    const int idx = blockIdx.x * 256 + threadIdx.x;
    if (idx >= 262144) return;
    const int lane = idx & 63, kk = (idx >> 6) & 1, g = (idx >> 7) & 3;
    const int w = (idx >> 9) & 3, kc = (idx >> 11) & 15, e0 = idx >> 15;
    const int row = g * 512 + e0 * 64 + w * 16 + (lane & 15);
    const int ks = (kc & 7) * 64 + kk * 32 + (lane >> 4) * 8;
    const bool lo = kc >= 8;
    shortx8 outv;
#pragma unroll
    for (int j = 0; j < 8; ++j) {
        const long si = (long)row * EDIM + ks + j;
        const float v = b ? (a[si] + b[si]) : a[si];
        const short hi = f2bf(v);
        outv[j] = lo ? f2bf(v - bf2f(hi)) : hi;
    }
    *(shortx8*)(o + (long)idx * 8) = outv;
}

// M1 = Wih1 @ enc_lin_W (K pad 34->64), swizzled, one thread per element.
__global__ __launch_bounds__(256) void swizzle_M1(const float* __restrict__ Wih1,
                                                  const float* __restrict__ encW,
                                                  short* __restrict__ o) {
    const int idx = blockIdx.x * 256 + threadIdx.x;
    if (idx >= 131072) return;
    const int u = idx >> 3, j = idx & 7;
    const int lane = u & 63, kk = (u >> 6) & 1, g = (u >> 7) & 3;
    const int w = (u >> 9) & 3, e0 = u >> 11;
    const int row = g * 512 + e0 * 64 + w * 16 + (lane & 15);
    const int k = kk * 32 + (lane >> 4) * 8 + j;
    float s = 0.f;
    if (k < POSE_D) {
        const float* wr = Wih1 + (long)row * EDIM;
        for (int jj = 0; jj < EDIM; ++jj) s += wr[jj] * encW[jj * POSE_D + k];
    }
    o[(long)u * 8 + j] = f2bf(s);
}

// out[b,f,p] = hf[b,:] . dec_lin_W[p,:] + dec_lin_b[p]  (pure fp32)
__global__ __launch_bounds__(64) void out_proj(const float* __restrict__ hf,
                                               const float* __restrict__ W,
                                               const float* __restrict__ bias,
                                               float* __restrict__ out, int f) {
    const int b = blockIdx.x;
    __shared__ float hrow[EDIM];
    const int lane = threadIdx.x;
    *(floatx4*)(hrow + lane * 8) = *(const floatx4*)(hf + (long)b * EDIM + lane * 8);
    *(floatx4*)(hrow + lane * 8 + 4) = *(const floatx4*)(hf + (long)b * EDIM + lane * 8 + 4);
    __syncthreads();
    if (lane < POSE_D) {
        float acc = bias[lane];
        const float* wr = W + (long)lane * EDIM;
        for (int e = 0; e < EDIM; e += 4) {
            const floatx4 wv = *(const floatx4*)(wr + e);
            acc += hrow[e] * wv[0] + hrow[e + 1] * wv[1] + hrow[e + 2] * wv[2] + hrow[e + 3] * wv[3];
        }
        out[((long)b * FUT + f) * POSE_D + lane] = acc;
    }
}

extern "C" void kernel_launch(void* const* d_in, const int* in_sizes, int n_in,
                              void* d_out, int out_size, void* d_ws, size_t ws_size,
                              hipStream_t stream) {
    const float* x = (const float*)d_in[0];
    const float* encW = (const float*)d_in[1];
    const float* encb = (const float*)d_in[2];
    const float* Wih1 = (const float*)d_in[3];
    const float* Whh1 = (const float*)d_in[4];
    const float* bih1 = (const float*)d_in[5];
    const float* bhh1 = (const float*)d_in[6];
    const float* Wih2 = (const float*)d_in[7];
    const float* Whh2 = (const float*)d_in[8];
    const float* bih2 = (const float*)d_in[9];
    const float* bhh2 = (const float*)d_in[10];
    const float* dWih = (const float*)d_in[11];
    const float* dWhh = (const float*)d_in[12];
    const float* dbih = (const float*)d_in[13];
    const float* dbhh = (const float*)d_in[14];
    const float* oW = (const float*)d_in[15];
    const float* ob = (const float*)d_in[16];
    float* out = (float*)d_out;

    char* ws = (char*)d_ws;
    size_t off = 0;
    auto alloc = [&](size_t bytes) -> char* {
        char* p = ws + off;
        off = (off + bytes + 255) & ~(size_t)255;
        return p;
    };
    const size_t HB = (size_t)BDIM * EDIM * 2;   // 2 MB bf16 state
    const size_t CB = (size_t)BDIM * EDIM * 4;   // 4 MB fp32 state
    const size_t WSZ = (size_t)262144 * 16;      // 4 MB swizzled split-W
    // zero-region (contiguous): h1_0, h2_0, c1, c2
    short* h1_0 = (short*)alloc(HB);
    short* h2_0 = (short*)alloc(HB);
    float* c1 = (float*)alloc(CB);
    float* c2 = (float*)alloc(CB);
    short* h1_1 = (short*)alloc(HB);
    short* h2_1 = (short*)alloc(HB);
    float* hf0 = (float*)alloc(CB);
    float* hf1 = (float*)alloc(CB);
    short* M1 = (short*)alloc((size_t)16384 * 16);
    short* sWhh1 = (short*)alloc(WSZ);
    short* sWih2 = (short*)alloc(WSZ);
    short* sWhh2 = (short*)alloc(WSZ);
    short* sdWhh = (short*)alloc(WSZ);
    short* sWsum = (short*)alloc(WSZ);
    float* bias1 = (float*)alloc(2048 * 4);
    float* bias2 = (float*)alloc(2048 * 4);
    float* biasd = (float*)alloc(2048 * 4);
    (void)ws_size; (void)in_sizes; (void)n_in; (void)out_size;

    zero_kernel<<<2048, 256, 0, stream>>>((unsigned int*)h1_0, (int)((2 * HB + 2 * CB) / 4));
    prep_bias<<<8, 256, 0, stream>>>(bih1, bhh1, Wih1, encb, bih2, bhh2, dbih, dbhh,
                                     bias1, bias2, biasd);
    swizzle_M1<<<512, 256, 0, stream>>>(Wih1, encW, M1);
    swizzle_w<<<1024, 256, 0, stream>>>(Whh1, nullptr, sWhh1);
    swizzle_w<<<1024, 256, 0, stream>>>(Wih2, nullptr, sWih2);
    swizzle_w<<<1024, 256, 0, stream>>>(Whh2, nullptr, sWhh2);
    swizzle_w<<<1024, 256, 0, stream>>>(dWhh, nullptr, sdWhh);
    swizzle_w<<<1024, 256, 0, stream>>>(dWih, dWhh, sWsum);

    dim3 grid(256), blk(512);
    short *h1p = h1_0, *h1n = h1_1, *h2p = h2_0, *h2n = h2_1;
    for (int t = 0; t < TSEQ; ++t) {
        lstm_cell_kernel<true, false, 1><<<grid, blk, 0, stream>>>(
            x + t * POSE_D, M1, h1p, sWhh1, nullptr, nullptr,
            bias1, c1, h1n, nullptr);
        lstm_cell_kernel<false, true, 1><<<grid, blk, 0, stream>>>(
            nullptr, nullptr, h1n, sWih2, h2p, sWhh2,
            bias2, c2, h2n, nullptr);
        short* t1 = h1p; h1p = h1n; h1n = t1;
        short* t2 = h2p; h2p = h2n; h2n = t2;
    }
    // decoder: bf16 h ping-pong reuses freed h1 buffers; fp32 copy for out_proj
    short* hd0 = h1_1;
    short* hd1 = h1_0;
    lstm_cell_kernel<false, false, 2><<<grid, blk, 0, stream>>>(
        nullptr, nullptr, h2p, sdWhh, nullptr, nullptr,
        biasd, c2, hd0, hf0);
    out_proj<<<BDIM, 64, 0, stream>>>(hf0, oW, ob, out, 0);
    short *dp = hd0, *dn = hd1;
    float *fp = hf0, *fn = hf1;
    for (int f = 1; f < FUT; ++f) {
        lstm_cell_kernel<false, false, 2><<<grid, blk, 0, stream>>>(
            nullptr, nullptr, dp, sWsum, nullptr, nullptr,
            biasd, c2, dn, fn);
        out_proj<<<BDIM, 64, 0, stream>>>(fn, oW, ob, out, f);
        short* tt = dp; dp = dn; dn = tt;
        float* tf = fp; fp = fn; fn = tf;
    }
}

// Round 9
// 3487.791 us; speedup vs baseline: 1.5506x; 1.3339x over previous
//
#include <hip/hip_runtime.h>

// Seq2Seq LSTM (B=2048, T=100, E=512, FUTURE=10, POSE=34). FP32 in/out.
// bf16 MFMA; encoder weights single bf16 plane (hi), decoder split hi+lo;
// h-state bf16, c-state fp32.
// R9: STEP FUSION. cell1(t+1) depends only on h1(t), so fuse
// [cell2(t); cell1(t+1)] into one kernel (99 launches replace 198):
//  - h1(t) panel staged ONCE, consumed by both Wih2 (cell2 ph1) and Whh1
//    (cell1) chunk streams.
//  - waves: (es2, rb, cs). cs=0 (4 waves) -> cell1 (x chunk + 8 Whh1);
//    cs=1 -> cell2 (8 Wih2, then 8 Whh2 after h2 re-stage). Each SIMD gets
//    one cs0 + one cs1 wave. Full-K per wave => NO kg reduction/overlay.
//  - cs0 runs cell1's epilogue while cs1 crunches the Whh2 phase.
// Tiling: 256 blocks = 16 e-slices (32 cols) x 16 R-groups (128 rows);
// W streamed global->VGPR from pre-swizzled layout, dbuf rotation.
// Endpoints (c1(0), c2(99)) + decoder use the R8 per-cell kernel.

#define TSEQ 100
#define FUT 10
#define POSE_D 34
#define EDIM 512
#define BDIM 2048

typedef __bf16 bf16x8 __attribute__((ext_vector_type(8)));
typedef float floatx4 __attribute__((ext_vector_type(4)));
typedef short shortx8 __attribute__((ext_vector_type(8)));

__device__ __forceinline__ float bf2f(short s) {
    unsigned int u = ((unsigned int)(unsigned short)s) << 16;
    float f;
    __builtin_memcpy(&f, &u, 4);
    return f;
}
__device__ __forceinline__ short f2bf(float f) {
    unsigned int u;
    __builtin_memcpy(&u, &f, 4);
    u += 0x7fffu + ((u >> 16) & 1u);
    return (short)(u >> 16);
}
__device__ __forceinline__ float fsig(float x) { return 1.f / (1.f + __expf(-x)); }
__device__ __forceinline__ float ftanh(float x) {
    float ax = fabsf(x);
    float t = __expf(-2.f * ax);
    float r = (1.f - t) / (1.f + t);
    return x < 0.f ? -r : r;
}

// Swizzled W stream (1KB wave units):
//   unit(e0,kcp,es,g,kk) = (((e0*16+kcp)*4+es)*4+g)*2+kk ; shorts = unit*512+lane*8
//   src row = g*512 + e0*64 + es*16 + (lane&15), k = (kcp&7)*64 + kk*32 + (lane>>4)*8
//   kcp<8 -> hi plane, kcp>=8 -> lo plane. M1 same with NW=1 (kcp=0).

// ---------------- fused [cell2(t); cell1(t+1)] kernel ----------------
__global__ __launch_bounds__(512, 2) void fused_step_kernel(
    const float* __restrict__ xnext, const short* __restrict__ M1,
    const short* __restrict__ h1, const short* __restrict__ sWhh1,
    const short* __restrict__ sWih2, const short* __restrict__ h2,
    const short* __restrict__ sWhh2,
    const float* __restrict__ bias1, const float* __restrict__ bias2,
    float* __restrict__ c1, float* __restrict__ c2,
    short* __restrict__ h1_out, short* __restrict__ h2_out) {
    __shared__ __align__(16) short lds[73728];  // x 16KB | panel 128KB
    const int tid = threadIdx.x;
    const int lane = tid & 63;
    const int wv = tid >> 6;
    const int es2 = wv & 1;
    const int rb = (wv >> 1) & 1;
    const int cs = wv >> 2;  // 0 -> cell1, 1 -> cell2
    const int m = lane & 15;
    const int q = lane >> 4;
    const int e16 = blockIdx.x & 15;
    const int R0 = (blockIdx.x >> 4) * 128;
    const int e0 = e16 >> 1;
    const int es = (e16 & 1) * 2 + es2;
    constexpr int AOFF = 8192;

    floatx4 acc[4][4];
#pragma unroll
    for (int ri = 0; ri < 4; ++ri)
#pragma unroll
        for (int g = 0; g < 4; ++g) acc[ri][g] = {0.f, 0.f, 0.f, 0.f};

    bf16x8 rW0[8], rW1[8];

    auto loadW = [&](const short* __restrict__ W, int kcp, bf16x8(&w_)[8]) {
        const short* P = W + (long)((e0 * 16 + kcp) * 4 + es) * 4096 + lane * 8;
#pragma unroll
        for (int i = 0; i < 8; ++i) w_[i] = *(const bf16x8*)(P + i * 512);
    };
    auto do_chunk = [&](int kcp, bf16x8(&w_)[8]) {
        const int k8 = (kcp & 7) * 8;
#pragma unroll
        for (int kk = 0; kk < 2; ++kk) {
            bf16x8 a[4];
#pragma unroll
            for (int ri = 0; ri < 4; ++ri) {
                const int row = rb * 64 + ri * 16 + m;
                a[ri] = *(const bf16x8*)(lds + AOFF + row * 512 +
                                         ((k8 | (((kk * 4 + q) ^ row) & 7)) << 3));
            }
#pragma unroll
            for (int ri = 0; ri < 4; ++ri)
#pragma unroll
                for (int g = 0; g < 4; ++g)
                    acc[ri][g] = __builtin_amdgcn_mfma_f32_16x16x32_bf16(
                        a[ri], w_[g * 2 + kk], acc[ri][g], 0, 0, 0);
        }
    };
    auto do_x = [&](bf16x8(&w_)[8]) {
#pragma unroll
        for (int kk = 0; kk < 2; ++kk) {
            bf16x8 a[4];
#pragma unroll
            for (int ri = 0; ri < 4; ++ri) {
                const int row = rb * 64 + ri * 16 + m;
                a[ri] = *(const bf16x8*)(lds + row * 64 + (((kk * 4 + q) ^ (row & 7)) << 3));
            }
#pragma unroll
            for (int ri = 0; ri < 4; ++ri)
#pragma unroll
                for (int g = 0; g < 4; ++g)
                    acc[ri][g] = __builtin_amdgcn_mfma_f32_16x16x32_bf16(
                        a[ri], w_[g * 2 + kk], acc[ri][g], 0, 0, 0);
        }
    };
    auto stageA = [&](const short* __restrict__ G) {
#pragma unroll
        for (int i = 0; i < 16; ++i) {
            const int u = tid + (i << 9);
            const int r = u >> 6, c = u & 63;
            const shortx8 v = *(const shortx8*)(G + (long)r * 512 + (c << 3));
            *(shortx8*)(lds + AOFF + r * 512 + (((c & 56) | ((c ^ r) & 7)) << 3)) = v;
        }
    };
    auto epilogue = [&](const float* __restrict__ bias, float* __restrict__ c_io,
                        short* __restrict__ h_out) {
        const int e = e16 * 32 + es2 * 16 + m;
        const float bi = bias[e];
        const float bfv = bias[512 + e];
        const float bg = bias[1024 + e];
        const float bo = bias[1536 + e];
#pragma unroll
        for (int ri = 0; ri < 4; ++ri) {
#pragma unroll
            for (int rg = 0; rg < 4; ++rg) {
                const int br = R0 + rb * 64 + ri * 16 + q * 4 + rg;  // C/D: row=q*4+reg
                const long cidx = (long)br * EDIM + e;
                const float iv = fsig(acc[ri][0][rg] + bi);
                const float fv = fsig(acc[ri][1][rg] + bfv);
                const float gv = ftanh(acc[ri][2][rg] + bg);
                const float ov = fsig(acc[ri][3][rg] + bo);
                const float cn = fv * c_io[cidx] + iv * gv;
                c_io[cidx] = cn;
                h_out[cidx] = f2bf(ov * ftanh(cn));
            }
        }
    };

    // ---- stage h1 panel + x panel; preload first W chunks ----
    floatx4 z = {0.f, 0.f, 0.f, 0.f};
    *(floatx4*)(lds + tid * 16) = z;
    *(floatx4*)(lds + tid * 16 + 8) = z;
    stageA(h1 + (long)R0 * 512);
    __syncthreads();  // zero visible before scalar x overwrite
    for (int idx = tid; idx < 128 * POSE_D; idx += 512) {
        const int r = idx / POSE_D;
        const int c = idx - r * POSE_D;
        lds[r * 64 + (((c >> 3) ^ (r & 7)) << 3) + (c & 7)] =
            f2bf(xnext[(long)(R0 + r) * (TSEQ * POSE_D) + c]);
    }
    if (cs == 0) {
        const short* P = M1 + (long)((e0 * 4 + es) * 8) * 512 + lane * 8;
#pragma unroll
        for (int i = 0; i < 8; ++i) rW0[i] = *(const bf16x8*)(P + i * 512);
        loadW(sWhh1, 0, rW1);
    } else {
        loadW(sWih2, 0, rW0);
        loadW(sWih2, 1, rW1);
    }
    __syncthreads();

    // ---- phase 1: both cells consume the h1 panel ----
    if (cs == 0) {
        do_x(rW0);  // gates1 += x(t+1) @ M1^T
#pragma unroll 1
        for (int k = 0; k < 8; ++k) {  // gates1 += h1 @ Whh1^T
            bf16x8(&buf)[8] = (k & 1) ? rW0 : rW1;
            do_chunk(k, buf);
            if (k + 2 < 8) loadW(sWhh1, k + 2, buf);
        }
    } else {
#pragma unroll 1
        for (int k = 0; k < 8; ++k) {  // gates2 += h1 @ Wih2^T
            bf16x8(&buf)[8] = (k & 1) ? rW1 : rW0;
            do_chunk(k, buf);
            if (k + 2 < 8) loadW(sWih2, k + 2, buf);
        }
    }

    // ---- re-stage panel with h2(t-1) ----
    __syncthreads();  // all h1-panel reads done
    stageA(h2 + (long)R0 * 512);
    if (cs == 1) {
        loadW(sWhh2, 0, rW0);
        loadW(sWhh2, 1, rW1);
    }
    __syncthreads();

    // ---- phase 2: cs1 finishes cell2 while cs0 writes cell1's state ----
    if (cs == 0) {
        epilogue(bias1, c1, h1_out);  // no LDS use
    } else {
#pragma unroll 1
        for (int k = 0; k < 8; ++k) {  // gates2 += h2 @ Whh2^T
            bf16x8(&buf)[8] = (k & 1) ? rW1 : rW0;
            do_chunk(k, buf);
            if (k + 2 < 8) loadW(sWhh2, k + 2, buf);
        }
        epilogue(bias2, c2, h2_out);
    }
}

// ---------------- per-cell kernel (endpoints + decoder), from R8 ----------------
template <bool HAS_X, bool TWO_H, int NP>
__global__ __launch_bounds__(512, 2) void lstm_cell_kernel(
    const float* __restrict__ xptr, const short* __restrict__ M1,
    const short* __restrict__ A1, const short* __restrict__ W1,
    const short* __restrict__ A2, const short* __restrict__ W2,
    const float* __restrict__ bias, float* __restrict__ c_io,
    short* __restrict__ h_out, float* __restrict__ hf_out) {
    __shared__ __align__(16) short lds[HAS_X ? 73728 : 65536];
    const int tid = threadIdx.x;
    const int lane = tid & 63;
    const int wv = tid >> 6;
    const int es2 = wv & 1;
    const int rb = (wv >> 1) & 1;
    const int kg = wv >> 2;
    const int m = lane & 15;
    const int q = lane >> 4;
    const int e16 = blockIdx.x & 15;
    const int R0 = (blockIdx.x >> 4) * 128;
    const int e0 = e16 >> 1;
    const int es = (e16 & 1) * 2 + es2;
    constexpr int PH = NP * 8;
    constexpr int AOFF = HAS_X ? 8192 : 0;

    floatx4 acc[4][4];
#pragma unroll
    for (int ri = 0; ri < 4; ++ri)
#pragma unroll
        for (int g = 0; g < 4; ++g) acc[ri][g] = {0.f, 0.f, 0.f, 0.f};

    bf16x8 rW0[8], rW1[8];

    auto loadW = [&](const short* __restrict__ W, int kcp, bf16x8(&w_)[8]) {
        const short* P = W + (long)((e0 * 16 + kcp) * 4 + es) * 4096 + lane * 8;
#pragma unroll
        for (int i = 0; i < 8; ++i) w_[i] = *(const bf16x8*)(P + i * 512);
    };
    auto loadM1 = [&](bf16x8(&w_)[8]) {
        const short* P = M1 + (long)((e0 * 4 + es) * 8) * 512 + lane * 8;
#pragma unroll
        for (int i = 0; i < 8; ++i) w_[i] = *(const bf16x8*)(P + i * 512);
    };
    auto do_chunk = [&](int kcp, bf16x8(&w_)[8]) {
        const int k8 = (kcp & 7) * 8;
#pragma unroll
        for (int kk = 0; kk < 2; ++kk) {
            bf16x8 a[4];
#pragma unroll
            for (int ri = 0; ri < 4; ++ri) {
                const int row = rb * 64 + ri * 16 + m;
                a[ri] = *(const bf16x8*)(lds + AOFF + row * 512 +
                                         ((k8 | (((kk * 4 + q) ^ row) & 7)) << 3));
            }
#pragma unroll
            for (int ri = 0; ri < 4; ++ri)
#pragma unroll
                for (int g = 0; g < 4; ++g)
                    acc[ri][g] = __builtin_amdgcn_mfma_f32_16x16x32_bf16(
                        a[ri], w_[g * 2 + kk], acc[ri][g], 0, 0, 0);
        }
    };
    auto do_x = [&](bf16x8(&w_)[8]) {
#pragma unroll
        for (int kk = 0; kk < 2; ++kk) {
            bf16x8 a[4];
#pragma unroll
            for (int ri = 0; ri < 4; ++ri) {
                const int row = rb * 64 + ri * 16 + m;
                a[ri] = *(const bf16x8*)(lds + row * 64 + (((kk * 4 + q) ^ (row & 7)) << 3));
            }
#pragma unroll
            for (int ri = 0; ri < 4; ++ri)
#pragma unroll
                for (int g = 0; g < 4; ++g)
                    acc[ri][g] = __builtin_amdgcn_mfma_f32_16x16x32_bf16(
                        a[ri], w_[g * 2 + kk], acc[ri][g], 0, 0, 0);
        }
    };
    auto stageA = [&](const short* __restrict__ G, int dst) {
#pragma unroll
        for (int i = 0; i < 16; ++i) {
            const int u = tid + (i << 9);
            const int r = u >> 6, c = u & 63;
            const shortx8 v = *(const shortx8*)(G + (long)r * 512 + (c << 3));
            *(shortx8*)(lds + dst + r * 512 + (((c & 56) | ((c ^ r) & 7)) << 3)) = v;
        }
    };
    auto loopP = [&](const short* __restrict__ W) {
        int c = kg;
#pragma unroll 1
        for (;;) {
            const int nxt = c + 2;
            if (nxt < PH) loadW(W, nxt, rW1);
            do_chunk(c, rW0);
            c = nxt;
            if (c >= PH) break;
            const int nx2 = c + 2;
            if (nx2 < PH) loadW(W, nx2, rW0);
            do_chunk(c, rW1);
            c = nx2;
            if (c >= PH) break;
        }
    };

    if constexpr (HAS_X) {
        constexpr int NT = 1 + PH;
        floatx4 z = {0.f, 0.f, 0.f, 0.f};
        *(floatx4*)(lds + tid * 16) = z;
        *(floatx4*)(lds + tid * 16 + 8) = z;
        stageA(A1 + (long)R0 * 512, AOFF);
        __syncthreads();
        for (int idx = tid; idx < 128 * POSE_D; idx += 512) {
            const int r = idx / POSE_D;
            const int c = idx - r * POSE_D;
            lds[r * 64 + (((c >> 3) ^ (r & 7)) << 3) + (c & 7)] =
                f2bf(xptr[(long)(R0 + r) * (TSEQ * POSE_D) + c]);
        }
        if (kg == 0) loadM1(rW0);
        else loadW(W1, 0, rW0);
        __syncthreads();
        int c = kg;
#pragma unroll 1
        for (;;) {
            const int nxt = c + 2;
            if (nxt < NT) loadW(W1, nxt - 1, rW1);
            if (c == 0) do_x(rW0);
            else do_chunk(c - 1, rW0);
            c = nxt;
            if (c >= NT) break;
            const int nx2 = c + 2;
            if (nx2 < NT) loadW(W1, nx2 - 1, rW0);
            do_chunk(c - 1, rW1);
            c = nx2;
            if (c >= NT) break;
        }
    } else {
        stageA(A1 + (long)R0 * 512, AOFF);
        loadW(W1, kg, rW0);
        __syncthreads();
        loopP(W1);
        if constexpr (TWO_H) {
            __syncthreads();
            stageA(A2 + (long)R0 * 512, AOFF);
            loadW(W2, kg, rW0);
            __syncthreads();
            loopP(W2);
        }
    }

    __syncthreads();
    float* ldsf = (float*)lds;
    const int L = (rb * 2 + es2) * 64 + lane;
    if (kg == 1) {
#pragma unroll
        for (int ri = 0; ri < 4; ++ri)
#pragma unroll
            for (int g = 0; g < 4; ++g) {
                const int f4 = ri * 4 + g;
                *(floatx4*)(ldsf + L * 68 + ((f4 ^ m) << 2)) = acc[ri][g];
            }
    }
    __syncthreads();
    if (kg == 0) {
#pragma unroll
        for (int ri = 0; ri < 4; ++ri)
#pragma unroll
            for (int g = 0; g < 4; ++g) {
                const int f4 = ri * 4 + g;
                acc[ri][g] += *(const floatx4*)(ldsf + L * 68 + ((f4 ^ m) << 2));
            }
        const int e = e16 * 32 + es2 * 16 + m;
        const float bi = bias[e];
        const float bfv = bias[512 + e];
        const float bg = bias[1024 + e];
        const float bo = bias[1536 + e];
#pragma unroll
        for (int ri = 0; ri < 4; ++ri) {
#pragma unroll
            for (int rg = 0; rg < 4; ++rg) {
                const int br = R0 + rb * 64 + ri * 16 + q * 4 + rg;
                const long cidx = (long)br * EDIM + e;
                const float iv = fsig(acc[ri][0][rg] + bi);
                const float fv = fsig(acc[ri][1][rg] + bfv);
                const float gv = ftanh(acc[ri][2][rg] + bg);
                const float ov = fsig(acc[ri][3][rg] + bo);
                const float cn = fv * c_io[cidx] + iv * gv;
                c_io[cidx] = cn;
                const float hv = ov * ftanh(cn);
                h_out[cidx] = f2bf(hv);
                if (hf_out) hf_out[cidx] = hv;
            }
        }
    }
}

__global__ __launch_bounds__(256) void zero_kernel(unsigned int* __restrict__ p, int n) {
    int i = blockIdx.x * 256 + threadIdx.x;
    const int stride = gridDim.x * 256;
    for (; i < n; i += stride) p[i] = 0u;
}

__global__ __launch_bounds__(256) void prep_bias(
    const float* __restrict__ bih1, const float* __restrict__ bhh1,
    const float* __restrict__ Wih1, const float* __restrict__ encb,
    const float* __restrict__ bih2, const float* __restrict__ bhh2,
    const float* __restrict__ dbih, const float* __restrict__ dbhh,
    float* __restrict__ bias1, float* __restrict__ bias2, float* __restrict__ biasd) {
    const int n = blockIdx.x * 256 + threadIdx.x;
    if (n >= 2048) return;
    float s = bih1[n] + bhh1[n];
    const float* wr = Wih1 + (long)n * EDIM;
    for (int j = 0; j < EDIM; ++j) s += wr[j] * encb[j];
    bias1[n] = s;
    bias2[n] = bih2[n] + bhh2[n];
    biasd[n] = dbih[n] + dbhh[n];
}

// Swizzle fp32 W[2048x512] (+optional addend) into hi|lo bf16 frag-stream;
// nkc limits chunk planes written (8 = hi only, 16 = hi+lo).
__global__ __launch_bounds__(256) void swizzle_w(const float* __restrict__ a,
                                                 const float* __restrict__ b,
                                                 short* __restrict__ o, int nkc) {
    const int idx = blockIdx.x * 256 + threadIdx.x;
    if (idx >= 262144) return;
    const int lane = idx & 63, kk = (idx >> 6) & 1, g = (idx >> 7) & 3;
    const int w = (idx >> 9) & 3, kc = (idx >> 11) & 15, e0 = idx >> 15;
    if (kc >= nkc) return;
    const int row = g * 512 + e0 * 64 + w * 16 + (lane & 15);
    const int ks = (kc & 7) * 64 + kk * 32 + (lane >> 4) * 8;
    const bool lo = kc >= 8;
    shortx8 outv;
#pragma unroll
    for (int j = 0; j < 8; ++j) {
        const long si = (long)row * EDIM + ks + j;
        const float v = b ? (a[si] + b[si]) : a[si];
        const short hi = f2bf(v);
        outv[j] = lo ? f2bf(v - bf2f(hi)) : hi;
    }
    *(shortx8*)(o + (long)idx * 8) = outv;
}

__global__ __launch_bounds__(256) void swizzle_M1(const float* __restrict__ Wih1,
                                                  const float* __restrict__ encW,
                                                  short* __restrict__ o) {
    const int idx = blockIdx.x * 256 + threadIdx.x;
    if (idx >= 131072) return;
    const int u = idx >> 3, j = idx & 7;
    const int lane = u & 63, kk = (u >> 6) & 1, g = (u >> 7) & 3;
    const int w = (u >> 9) & 3, e0 = u >> 11;
    const int row = g * 512 + e0 * 64 + w * 16 + (lane & 15);
    const int k = kk * 32 + (lane >> 4) * 8 + j;
    float s = 0.f;
    if (k < POSE_D) {
        const float* wr = Wih1 + (long)row * EDIM;
        for (int jj = 0; jj < EDIM; ++jj) s += wr[jj] * encW[jj * POSE_D + k];
    }
    o[(long)u * 8 + j] = f2bf(s);
}

__global__ __launch_bounds__(64) void out_proj(const float* __restrict__ hf,
                                               const float* __restrict__ W,
                                               const float* __restrict__ bias,
                                               float* __restrict__ out, int f) {
    const int b = blockIdx.x;
    __shared__ float hrow[EDIM];
    const int lane = threadIdx.x;
    *(floatx4*)(hrow + lane * 8) = *(const floatx4*)(hf + (long)b * EDIM + lane * 8);
    *(floatx4*)(hrow + lane * 8 + 4) = *(const floatx4*)(hf + (long)b * EDIM + lane * 8 + 4);
    __syncthreads();
    if (lane < POSE_D) {
        float acc = bias[lane];
        const float* wr = W + (long)lane * EDIM;
        for (int e = 0; e < EDIM; e += 4) {
            const floatx4 wv = *(const floatx4*)(wr + e);
            acc += hrow[e] * wv[0] + hrow[e + 1] * wv[1] + hrow[e + 2] * wv[2] + hrow[e + 3] * wv[3];
        }
        out[((long)b * FUT + f) * POSE_D + lane] = acc;
    }
}

extern "C" void kernel_launch(void* const* d_in, const int* in_sizes, int n_in,
                              void* d_out, int out_size, void* d_ws, size_t ws_size,
                              hipStream_t stream) {
    const float* x = (const float*)d_in[0];
    const float* encW = (const float*)d_in[1];
    const float* encb = (const float*)d_in[2];
    const float* Wih1 = (const float*)d_in[3];
    const float* Whh1 = (const float*)d_in[4];
    const float* bih1 = (const float*)d_in[5];
    const float* bhh1 = (const float*)d_in[6];
    const float* Wih2 = (const float*)d_in[7];
    const float* Whh2 = (const float*)d_in[8];
    const float* bih2 = (const float*)d_in[9];
    const float* bhh2 = (const float*)d_in[10];
    const float* dWih = (const float*)d_in[11];
    const float* dWhh = (const float*)d_in[12];
    const float* dbih = (const float*)d_in[13];
    const float* dbhh = (const float*)d_in[14];
    const float* oW = (const float*)d_in[15];
    const float* ob = (const float*)d_in[16];
    float* out = (float*)d_out;

    char* ws = (char*)d_ws;
    size_t off = 0;
    auto alloc = [&](size_t bytes) -> char* {
        char* p = ws + off;
        off = (off + bytes + 255) & ~(size_t)255;
        return p;
    };
    const size_t HB = (size_t)BDIM * EDIM * 2;
    const size_t CB = (size_t)BDIM * EDIM * 4;
    const size_t WSZ = (size_t)262144 * 16;
    // zero-region (contiguous): h1_0, h2_0, c1, c2
    short* h1_0 = (short*)alloc(HB);
    short* h2_0 = (short*)alloc(HB);
    float* c1 = (float*)alloc(CB);
    float* c2 = (float*)alloc(CB);
    short* h1_1 = (short*)alloc(HB);
    short* h2_1 = (short*)alloc(HB);
    float* hf0 = (float*)alloc(CB);
    float* hf1 = (float*)alloc(CB);
    short* M1 = (short*)alloc((size_t)16384 * 16);
    short* sWhh1 = (short*)alloc(WSZ);
    short* sWih2 = (short*)alloc(WSZ);
    short* sWhh2 = (short*)alloc(WSZ);
    short* sdWhh = (short*)alloc(WSZ);
    short* sWsum = (short*)alloc(WSZ);
    float* bias1 = (float*)alloc(2048 * 4);
    float* bias2 = (float*)alloc(2048 * 4);
    float* biasd = (float*)alloc(2048 * 4);
    (void)ws_size; (void)in_sizes; (void)n_in; (void)out_size;

    zero_kernel<<<2048, 256, 0, stream>>>((unsigned int*)h1_0, (int)((2 * HB + 2 * CB) / 4));
    prep_bias<<<8, 256, 0, stream>>>(bih1, bhh1, Wih1, encb, bih2, bhh2, dbih, dbhh,
                                     bias1, bias2, biasd);
    swizzle_M1<<<512, 256, 0, stream>>>(Wih1, encW, M1);
    swizzle_w<<<1024, 256, 0, stream>>>(Whh1, nullptr, sWhh1, 8);
    swizzle_w<<<1024, 256, 0, stream>>>(Wih2, nullptr, sWih2, 8);
    swizzle_w<<<1024, 256, 0, stream>>>(Whh2, nullptr, sWhh2, 8);
    swizzle_w<<<1024, 256, 0, stream>>>(dWhh, nullptr, sdWhh, 16);
    swizzle_w<<<1024, 256, 0, stream>>>(dWih, dWhh, sWsum, 16);

    dim3 grid(256), blk(512);
    // c1(0): gates1 = x(0)@M1 + 0@Whh1 (h1_0 is zeros) -> h1_1
    lstm_cell_kernel<true, false, 1><<<grid, blk, 0, stream>>>(
        x, M1, h1_0, sWhh1, nullptr, nullptr, bias1, c1, h1_1, nullptr);
    // fused steps t=0..98: [cell2(t); cell1(t+1)]
    short *h1c = h1_1, *h1n = h1_0, *h2c = h2_0, *h2n = h2_1;
    for (int t = 0; t < TSEQ - 1; ++t) {
        fused_step_kernel<<<grid, blk, 0, stream>>>(
            x + (t + 1) * POSE_D, M1, h1c, sWhh1, sWih2, h2c, sWhh2,
            bias1, bias2, c1, c2, h1n, h2n);
        short* s1 = h1c; h1c = h1n; h1n = s1;
        short* s2 = h2c; h2c = h2n; h2n = s2;
    }
    // c2(99): gates2 = h1(99)@Wih2 + h2(98)@Whh2 -> h2n
    lstm_cell_kernel<false, true, 1><<<grid, blk, 0, stream>>>(
        nullptr, nullptr, h1c, sWih2, h2c, sWhh2, bias2, c2, h2n, nullptr);
    short* h2fin = h2n;

    // decoder (split weights): bf16 ping-pong + fp32 copies for out_proj
    short* hd0 = h1c;
    short* hd1 = h1n;
    lstm_cell_kernel<false, false, 2><<<grid, blk, 0, stream>>>(
        nullptr, nullptr, h2fin, sdWhh, nullptr, nullptr, biasd, c2, hd0, hf0);
    out_proj<<<BDIM, 64, 0, stream>>>(hf0, oW, ob, out, 0);
    short *dp = hd0, *dn = hd1;
    float *fp = hf0, *fn = hf1;
    for (int f = 1; f < FUT; ++f) {
        lstm_cell_kernel<false, false, 2><<<grid, blk, 0, stream>>>(
            nullptr, nullptr, dp, sWsum, nullptr, nullptr, biasd, c2, dn, fn);
        out_proj<<<BDIM, 64, 0, stream>>>(fn, oW, ob, out, f);
        short* tt = dp; dp = dn; dn = tt;
        float* tf = fp; fp = fn; fn = tf;
    }
}